// Round 18
// baseline (588.696 us; speedup 1.0000x reference)
//
#include <hip/hip_runtime.h>

#define NH 32
#define HD 128
#define PBS 16
#define HIDDEN (NH * HD)   // 4096
#define QKVN (3 * HIDDEN)  // 12288
#define NSPLIT 8
#define KC 512             // k-chunk staged in LDS (gemv)

// QKV GEMV with fused bias + RoPE. NR=2 rows/wave -> 1536 blocks (6/CU).
// bid < 1024: q/k region. Wave handles 1 RoPE pair = rows {r0, r0+64}.
// bid >= 1024: v region. Wave handles 2 contiguous rows, no rotation.
__global__ __launch_bounds__(256) void gemv_qkv_rope(const float* __restrict__ x,
                                                     const float* __restrict__ W,
                                                     const float* __restrict__ bias,
                                                     const float* __restrict__ cosb,
                                                     const float* __restrict__ sinb,
                                                     float* __restrict__ qkv) {
    __shared__ float xs[8][KC];
    const int tid  = threadIdx.x;
    const int lane = tid & 63;
    const int wid  = tid >> 6;
    const int bid  = blockIdx.x;

    // ---- row selection ----
    int rows[2];
    int d0 = 0;
    bool rope;
    if (bid < 1024) {
        rope = true;
        const int p = bid * 4 + wid;          // pair index, 0..4095
        const int part = p >> 11;             // 0=q, 1=k
        const int q = p & 2047;
        const int h = q >> 6;
        d0 = q & 63;
        const int r0 = part * HIDDEN + h * HD + d0;
        rows[0] = r0; rows[1] = r0 + 64;
    } else {
        rope = false;
        const int n0 = 2 * HIDDEN + (bid - 1024) * 8 + wid * 2;
        rows[0] = n0; rows[1] = n0 + 1;
    }
    const float* wr[2];
#pragma unroll
    for (int r = 0; r < 2; ++r) wr[r] = W + (size_t)rows[r] * HIDDEN;

    float acc[2][8];
#pragma unroll
    for (int r = 0; r < 2; ++r)
#pragma unroll
        for (int b = 0; b < 8; ++b) acc[r][b] = 0.f;

    for (int kc = 0; kc < HIDDEN; kc += KC) {
        __syncthreads();
        {
            const int bq  = tid >> 5;
            const int t32 = tid & 31;
            const float* xb = x + (size_t)bq * HIDDEN + kc;
#pragma unroll
            for (int j = 0; j < 4; ++j) {
                const int off = (t32 + j * 32) * 4;
                *reinterpret_cast<float4*>(&xs[bq][off]) =
                    *reinterpret_cast<const float4*>(xb + off);
            }
        }
        __syncthreads();
#pragma unroll
        for (int j = 0; j < 2; ++j) {
            const int kk = lane * 4 + j * 256;
            float4 w4[2];
#pragma unroll
            for (int r = 0; r < 2; ++r)
                w4[r] = *reinterpret_cast<const float4*>(wr[r] + kc + kk);
#pragma unroll
            for (int b = 0; b < 8; ++b) {
                const float4 x4 = *reinterpret_cast<const float4*>(&xs[b][kk]);
#pragma unroll
                for (int r = 0; r < 2; ++r)
                    acc[r][b] += w4[r].x * x4.x + w4[r].y * x4.y +
                                 w4[r].z * x4.z + w4[r].w * x4.w;
            }
        }
    }
#pragma unroll
    for (int r = 0; r < 2; ++r)
#pragma unroll
        for (int b = 0; b < 8; ++b)
#pragma unroll
            for (int off = 32; off > 0; off >>= 1)
                acc[r][b] += __shfl_xor(acc[r][b], off, 64);

    if (lane == 0) {
        if (rope) {
#pragma unroll
            for (int b = 0; b < 8; ++b) {
                const float v0 = acc[0][b] + bias[rows[0]];
                const float v1 = acc[1][b] + bias[rows[1]];
                const float c0 = cosb[b * 64 + d0];
                const float s0 = sinb[b * 64 + d0];
                float* qb = qkv + (size_t)b * QKVN;
                qb[rows[0]] = v0 * c0 - v1 * s0;
                qb[rows[1]] = v0 * s0 + v1 * c0;
            }
        } else {
#pragma unroll
            for (int b = 0; b < 8; ++b) {
                float* qb = qkv + (size_t)b * QKVN;
#pragma unroll
                for (int r = 0; r < 2; ++r)
                    qb[rows[r]] = acc[r][b] + bias[rows[r]];
            }
        }
    }
}

// O-proj GEMV, NR rows/wave, LDS-staged x.
template <int NR>
__global__ __launch_bounds__(256) void gemv_lds(const float* __restrict__ x,
                                                const float* __restrict__ W,
                                                float* __restrict__ out,
                                                int N, int K) {
    __shared__ float xs[8][KC];
    const int tid  = threadIdx.x;
    const int lane = tid & 63;
    const int wid  = tid >> 6;
    const int n0   = blockIdx.x * (NR * 4) + wid * NR;
    const float* w0 = W + (size_t)n0 * K;

    float acc[NR][8];
#pragma unroll
    for (int r = 0; r < NR; ++r)
#pragma unroll
        for (int b = 0; b < 8; ++b) acc[r][b] = 0.f;

    for (int kc = 0; kc < K; kc += KC) {
        __syncthreads();
        {
            const int bq  = tid >> 5;
            const int t32 = tid & 31;
            const float* xb = x + (size_t)bq * K + kc;
#pragma unroll
            for (int j = 0; j < 4; ++j) {
                const int off = (t32 + j * 32) * 4;
                *reinterpret_cast<float4*>(&xs[bq][off]) =
                    *reinterpret_cast<const float4*>(xb + off);
            }
        }
        __syncthreads();
#pragma unroll
        for (int j = 0; j < 2; ++j) {
            const int kk = lane * 4 + j * 256;
            float4 w4[NR];
#pragma unroll
            for (int r = 0; r < NR; ++r)
                w4[r] = *reinterpret_cast<const float4*>(w0 + (size_t)r * K + kc + kk);
#pragma unroll
            for (int b = 0; b < 8; ++b) {
                const float4 x4 = *reinterpret_cast<const float4*>(&xs[b][kk]);
#pragma unroll
                for (int r = 0; r < NR; ++r)
                    acc[r][b] += w4[r].x * x4.x + w4[r].y * x4.y +
                                 w4[r].z * x4.z + w4[r].w * x4.w;
            }
        }
    }
#pragma unroll
    for (int r = 0; r < NR; ++r)
#pragma unroll
        for (int b = 0; b < 8; ++b)
#pragma unroll
            for (int off = 32; off > 0; off >>= 1)
                acc[r][b] += __shfl_xor(acc[r][b], off, 64);
    if (lane == 0) {
#pragma unroll
        for (int r = 0; r < NR; ++r)
#pragma unroll
            for (int b = 0; b < 8; ++b)
                out[(size_t)b * N + n0 + r] = acc[r][b];
    }
}

// One-pass online-softmax partial (R9 known-good) with FUSED final reduce:
// the 8th block to finish a bh performs the 8-way partial merge inline
// (last-block-done pattern, device-scope atomics + threadfences).
__global__ __launch_bounds__(256) void attn_part(const float* __restrict__ qkv,
                                                 const float* __restrict__ k_cache,
                                                 const float* __restrict__ v_cache,
                                                 const int* __restrict__ block_tables,
                                                 const int* __restrict__ slots,
                                                 const int* __restrict__ lengths,
                                                 float* __restrict__ part_o,
                                                 float* __restrict__ part_ml,
                                                 int* __restrict__ counters,
                                                 float* __restrict__ attn_out,
                                                 int S, int max_blocks) {
    const int split = blockIdx.x % NSPLIT;
    const int bh    = blockIdx.x / NSPLIT;
    const int b     = bh >> 5;
    const int h     = bh & 31;
    const int SP    = S / NSPLIT;       // 256
    const int base  = split * SP;

    __shared__ int   bt[64];
    __shared__ float stage[4][HD + 2];
    __shared__ int   lastflag;

    const int tid  = threadIdx.x;
    const int lane = tid & 63;
    const int wid  = tid >> 6;
    const int half = lane >> 5;
    const int l32  = lane & 31;

    for (int i = tid; i < SP / PBS; i += blockDim.x)
        bt[i] = block_tables[b * max_blocks + base / PBS + i];
    __syncthreads();

    const int slot_b = slots[b];
    const int len    = lengths[b];
    const float scale = 0.088388347648318447f;  // 1/sqrt(128)

    const float* qp   = qkv + (size_t)b * QKVN + h * HD;
    const float* newk = qp + HIDDEN;
    const float* newv = qp + 2 * HIDDEN;
    const float4 q4 = *reinterpret_cast<const float4*>(qp + l32 * 4);

    float m = -1e30f, l = 0.f;
    float4 acc[8];
#pragma unroll
    for (int u = 0; u < 8; ++u) acc[u] = make_float4(0.f, 0.f, 0.f, 0.f);

    for (int s0 = wid * 16; s0 < SP; s0 += 64) {
        float4 k4[8], v4[8];
#pragma unroll
        for (int u = 0; u < 8; ++u) {
            const int p = s0 + u * 2 + half;
            const int idx = bt[p >> 4] * PBS + (p & (PBS - 1));
            const bool fresh = (idx == slot_b);
            k4[u] = fresh ? *reinterpret_cast<const float4*>(newk + l32 * 4)
                          : *reinterpret_cast<const float4*>(
                                k_cache + (size_t)idx * HIDDEN + h * HD + l32 * 4);
            v4[u] = fresh ? *reinterpret_cast<const float4*>(newv + l32 * 4)
                          : *reinterpret_cast<const float4*>(
                                v_cache + (size_t)idx * HIDDEN + h * HD + l32 * 4);
        }
        float sc[8];
#pragma unroll
        for (int u = 0; u < 8; ++u) {
            float d = k4[u].x * q4.x + k4[u].y * q4.y + k4[u].z * q4.z + k4[u].w * q4.w;
#pragma unroll
            for (int off = 16; off > 0; off >>= 1) d += __shfl_xor(d, off, 64);
            const int p = s0 + u * 2 + half;
            sc[u] = (base + p < len) ? d * scale : -1e30f;
        }
        float pm = sc[0];
#pragma unroll
        for (int u = 1; u < 8; ++u) pm = fmaxf(pm, sc[u]);
        const float mn = fmaxf(m, pm);
        const float r = __expf(m - mn);
        m = mn;
        l *= r;
        float pu[8];
#pragma unroll
        for (int u = 0; u < 8; ++u) {
            pu[u] = __expf(sc[u] - mn);
            l += pu[u];
        }
#pragma unroll
        for (int u = 0; u < 8; ++u) {
            acc[u].x = fmaf(pu[u], v4[u].x, acc[u].x * r);
            acc[u].y = fmaf(pu[u], v4[u].y, acc[u].y * r);
            acc[u].z = fmaf(pu[u], v4[u].z, acc[u].z * r);
            acc[u].w = fmaf(pu[u], v4[u].w, acc[u].w * r);
        }
    }
    float4 a = acc[0];
#pragma unroll
    for (int u = 1; u < 8; ++u) {
        a.x += acc[u].x; a.y += acc[u].y; a.z += acc[u].z; a.w += acc[u].w;
    }
    {
        const float m2 = __shfl_xor(m, 32, 64);
        const float l2 = __shfl_xor(l, 32, 64);
        float4 a2;
        a2.x = __shfl_xor(a.x, 32, 64);
        a2.y = __shfl_xor(a.y, 32, 64);
        a2.z = __shfl_xor(a.z, 32, 64);
        a2.w = __shfl_xor(a.w, 32, 64);
        const float M  = fmaxf(m, m2);
        const float e1 = __expf(m - M);
        const float e2 = __expf(m2 - M);
        l = l * e1 + l2 * e2;
        a.x = a.x * e1 + a2.x * e2;
        a.y = a.y * e1 + a2.y * e2;
        a.z = a.z * e1 + a2.z * e2;
        a.w = a.w * e1 + a2.w * e2;
        m = M;
    }
    if (half == 0) {
        *reinterpret_cast<float4*>(&stage[wid][l32 * 4]) = a;
        if (l32 == 0) { stage[wid][HD] = m; stage[wid][HD + 1] = l; }
    }
    __syncthreads();
    if (wid == 0) {
        float M4 = stage[0][HD];
#pragma unroll
        for (int w = 1; w < 4; ++w) M4 = fmaxf(M4, stage[w][HD]);
        float L = 0.f, t0 = 0.f, t1 = 0.f;
#pragma unroll
        for (int w = 0; w < 4; ++w) {
            const float e = __expf(stage[w][HD] - M4);
            L  += stage[w][HD + 1] * e;
            t0 += stage[w][lane * 2] * e;
            t1 += stage[w][lane * 2 + 1] * e;
        }
        float* po = part_o + ((size_t)bh * NSPLIT + split) * HD;
        po[lane * 2]     = t0;
        po[lane * 2 + 1] = t1;
        if (lane == 0) {
            part_ml[((size_t)bh * NSPLIT + split) * 2]     = M4;
            part_ml[((size_t)bh * NSPLIT + split) * 2 + 1] = L;
        }
    }

    // ---- fused final reduce: last block of this bh merges the 8 partials ----
    __threadfence();            // release: make this block's writes visible
    __syncthreads();            // all threads' fences complete
    if (tid == 0) {
        const int prev = atomicAdd(&counters[bh], 1);
        lastflag = (prev == NSPLIT - 1);
    }
    __syncthreads();
    if (lastflag) {
        __threadfence();        // acquire: see other blocks' partials
        if (tid < HD) {
            const int d = tid;
            float M = -1e30f;
#pragma unroll
            for (int i = 0; i < NSPLIT; ++i)
                M = fmaxf(M, part_ml[((size_t)bh * NSPLIT + i) * 2]);
            float L = 0.f, o = 0.f;
#pragma unroll
            for (int i = 0; i < NSPLIT; ++i) {
                const float mi = part_ml[((size_t)bh * NSPLIT + i) * 2];
                const float li = part_ml[((size_t)bh * NSPLIT + i) * 2 + 1];
                const float w  = __expf(mi - M);
                L += li * w;
                o += part_o[((size_t)bh * NSPLIT + i) * HD + d] * w;
            }
            attn_out[(size_t)bh * HD + d] = o / L;
        }
    }
}

extern "C" void kernel_launch(void* const* d_in, const int* in_sizes, int n_in,
                              void* d_out, int out_size, void* d_ws, size_t ws_size,
                              hipStream_t stream) {
    const float* hidden  = (const float*)d_in[0];
    const float* cosb    = (const float*)d_in[1];
    const float* sinb    = (const float*)d_in[2];
    const float* w_qkv   = (const float*)d_in[3];
    const float* b_qkv   = (const float*)d_in[4];
    const float* w_o     = (const float*)d_in[5];
    const float* k_cache = (const float*)d_in[6];
    const float* v_cache = (const float*)d_in[7];
    const int*   btab    = (const int*)d_in[8];
    const int*   slots   = (const int*)d_in[9];
    const int*   lens    = (const int*)d_in[10];

    const int B = in_sizes[0] / HIDDEN;      // 8
    const int max_blocks = in_sizes[8] / B;  // 128
    const int S = max_blocks * PBS;          // 2048

    float* qkv     = (float*)d_ws;                        // [B][QKVN] (roped q,k)
    float* attn    = qkv + (size_t)B * QKVN;              // [B][HIDDEN]
    float* part_o  = attn + (size_t)B * HIDDEN;           // [B*NH*NSPLIT][HD]
    float* part_ml = part_o + (size_t)B * NH * NSPLIT * HD;  // [B*NH*NSPLIT][2]
    int*   counters = (int*)(part_ml + (size_t)B * NH * NSPLIT * 2);  // [B*NH]
    float* out     = (float*)d_out;

    // zero the completion counters (graph-capture-legal)
    hipMemsetAsync(counters, 0, (size_t)B * NH * sizeof(int), stream);

    // 1) qkv = hidden @ w_qkv^T + b_qkv, RoPE fused (NR=2, 1536 blocks, 6/CU)
    gemv_qkv_rope<<<1536, 256, 0, stream>>>(hidden, w_qkv, b_qkv, cosb, sinb, qkv);

    // 2) paged attention partials + fused last-block reduce
    attn_part<<<B * NH * NSPLIT, 256, 0, stream>>>(qkv, k_cache, v_cache,
                                                   btab, slots, lens,
                                                   part_o, part_ml, counters,
                                                   attn, S, max_blocks);

    // 3) out = attn @ w_o^T   (NR=1, 1024 blocks, 4/CU)
    gemv_lds<1><<<HIDDEN / 4, 256, 0, stream>>>(attn, w_o, out, HIDDEN, HIDDEN);
}

// Round 19
// 169.356 us; speedup vs baseline: 3.4761x; 3.4761x over previous
//
#include <hip/hip_runtime.h>

#define NH 32
#define HD 128
#define PBS 16
#define HIDDEN (NH * HD)   // 4096
#define QKVN (3 * HIDDEN)  // 12288
#define NSPLIT 8
#define KC 512             // k-chunk staged in LDS (gemv)

// QKV GEMV with fused bias + RoPE. NR=2 rows/wave -> 1536 blocks (6/CU).
// bid < 1024: q/k region. Wave handles 1 RoPE pair = rows {r0, r0+64}.
// bid >= 1024: v region. Wave handles 2 contiguous rows, no rotation.
__global__ __launch_bounds__(256) void gemv_qkv_rope(const float* __restrict__ x,
                                                     const float* __restrict__ W,
                                                     const float* __restrict__ bias,
                                                     const float* __restrict__ cosb,
                                                     const float* __restrict__ sinb,
                                                     float* __restrict__ qkv) {
    __shared__ float xs[8][KC];
    const int tid  = threadIdx.x;
    const int lane = tid & 63;
    const int wid  = tid >> 6;
    const int bid  = blockIdx.x;

    // ---- row selection ----
    int rows[2];
    int d0 = 0;
    bool rope;
    if (bid < 1024) {
        rope = true;
        const int p = bid * 4 + wid;          // pair index, 0..4095
        const int part = p >> 11;             // 0=q, 1=k
        const int q = p & 2047;
        const int h = q >> 6;
        d0 = q & 63;
        const int r0 = part * HIDDEN + h * HD + d0;
        rows[0] = r0; rows[1] = r0 + 64;
    } else {
        rope = false;
        const int n0 = 2 * HIDDEN + (bid - 1024) * 8 + wid * 2;
        rows[0] = n0; rows[1] = n0 + 1;
    }
    const float* wr[2];
#pragma unroll
    for (int r = 0; r < 2; ++r) wr[r] = W + (size_t)rows[r] * HIDDEN;

    float acc[2][8];
#pragma unroll
    for (int r = 0; r < 2; ++r)
#pragma unroll
        for (int b = 0; b < 8; ++b) acc[r][b] = 0.f;

    for (int kc = 0; kc < HIDDEN; kc += KC) {
        __syncthreads();
        {
            const int bq  = tid >> 5;
            const int t32 = tid & 31;
            const float* xb = x + (size_t)bq * HIDDEN + kc;
#pragma unroll
            for (int j = 0; j < 4; ++j) {
                const int off = (t32 + j * 32) * 4;
                *reinterpret_cast<float4*>(&xs[bq][off]) =
                    *reinterpret_cast<const float4*>(xb + off);
            }
        }
        __syncthreads();
#pragma unroll
        for (int j = 0; j < 2; ++j) {
            const int kk = lane * 4 + j * 256;
            float4 w4[2];
#pragma unroll
            for (int r = 0; r < 2; ++r)
                w4[r] = *reinterpret_cast<const float4*>(wr[r] + kc + kk);
#pragma unroll
            for (int b = 0; b < 8; ++b) {
                const float4 x4 = *reinterpret_cast<const float4*>(&xs[b][kk]);
#pragma unroll
                for (int r = 0; r < 2; ++r)
                    acc[r][b] += w4[r].x * x4.x + w4[r].y * x4.y +
                                 w4[r].z * x4.z + w4[r].w * x4.w;
            }
        }
    }
#pragma unroll
    for (int r = 0; r < 2; ++r)
#pragma unroll
        for (int b = 0; b < 8; ++b)
#pragma unroll
            for (int off = 32; off > 0; off >>= 1)
                acc[r][b] += __shfl_xor(acc[r][b], off, 64);

    if (lane == 0) {
        if (rope) {
#pragma unroll
            for (int b = 0; b < 8; ++b) {
                const float v0 = acc[0][b] + bias[rows[0]];
                const float v1 = acc[1][b] + bias[rows[1]];
                const float c0 = cosb[b * 64 + d0];
                const float s0 = sinb[b * 64 + d0];
                float* qb = qkv + (size_t)b * QKVN;
                qb[rows[0]] = v0 * c0 - v1 * s0;
                qb[rows[1]] = v0 * s0 + v1 * c0;
            }
        } else {
#pragma unroll
            for (int b = 0; b < 8; ++b) {
                float* qb = qkv + (size_t)b * QKVN;
#pragma unroll
                for (int r = 0; r < 2; ++r)
                    qb[rows[r]] = acc[r][b] + bias[rows[r]];
            }
        }
    }
}

// O-proj GEMV, NR rows/wave, LDS-staged x.
template <int NR>
__global__ __launch_bounds__(256) void gemv_lds(const float* __restrict__ x,
                                                const float* __restrict__ W,
                                                float* __restrict__ out,
                                                int N, int K) {
    __shared__ float xs[8][KC];
    const int tid  = threadIdx.x;
    const int lane = tid & 63;
    const int wid  = tid >> 6;
    const int n0   = blockIdx.x * (NR * 4) + wid * NR;
    const float* w0 = W + (size_t)n0 * K;

    float acc[NR][8];
#pragma unroll
    for (int r = 0; r < NR; ++r)
#pragma unroll
        for (int b = 0; b < 8; ++b) acc[r][b] = 0.f;

    for (int kc = 0; kc < K; kc += KC) {
        __syncthreads();
        {
            const int bq  = tid >> 5;
            const int t32 = tid & 31;
            const float* xb = x + (size_t)bq * K + kc;
#pragma unroll
            for (int j = 0; j < 4; ++j) {
                const int off = (t32 + j * 32) * 4;
                *reinterpret_cast<float4*>(&xs[bq][off]) =
                    *reinterpret_cast<const float4*>(xb + off);
            }
        }
        __syncthreads();
#pragma unroll
        for (int j = 0; j < 2; ++j) {
            const int kk = lane * 4 + j * 256;
            float4 w4[NR];
#pragma unroll
            for (int r = 0; r < NR; ++r)
                w4[r] = *reinterpret_cast<const float4*>(w0 + (size_t)r * K + kc + kk);
#pragma unroll
            for (int b = 0; b < 8; ++b) {
                const float4 x4 = *reinterpret_cast<const float4*>(&xs[b][kk]);
#pragma unroll
                for (int r = 0; r < NR; ++r)
                    acc[r][b] += w4[r].x * x4.x + w4[r].y * x4.y +
                                 w4[r].z * x4.z + w4[r].w * x4.w;
            }
        }
    }
#pragma unroll
    for (int r = 0; r < NR; ++r)
#pragma unroll
        for (int b = 0; b < 8; ++b)
#pragma unroll
            for (int off = 32; off > 0; off >>= 1)
                acc[r][b] += __shfl_xor(acc[r][b], off, 64);
    if (lane == 0) {
#pragma unroll
        for (int r = 0; r < NR; ++r)
#pragma unroll
            for (int b = 0; b < 8; ++b)
                out[(size_t)b * N + n0 + r] = acc[r][b];
    }
}

// One-pass online-softmax partial (R9 known-good).
__global__ __launch_bounds__(256) void attn_part(const float* __restrict__ qkv,
                                                 const float* __restrict__ k_cache,
                                                 const float* __restrict__ v_cache,
                                                 const int* __restrict__ block_tables,
                                                 const int* __restrict__ slots,
                                                 const int* __restrict__ lengths,
                                                 float* __restrict__ part_o,
                                                 float* __restrict__ part_ml,
                                                 int S, int max_blocks) {
    const int split = blockIdx.x % NSPLIT;
    const int bh    = blockIdx.x / NSPLIT;
    const int b     = bh >> 5;
    const int h     = bh & 31;
    const int SP    = S / NSPLIT;       // 256
    const int base  = split * SP;

    __shared__ int   bt[64];
    __shared__ float stage[4][HD + 2];

    const int tid  = threadIdx.x;
    const int lane = tid & 63;
    const int wid  = tid >> 6;
    const int half = lane >> 5;
    const int l32  = lane & 31;

    for (int i = tid; i < SP / PBS; i += blockDim.x)
        bt[i] = block_tables[b * max_blocks + base / PBS + i];
    __syncthreads();

    const int slot_b = slots[b];
    const int len    = lengths[b];
    const float scale = 0.088388347648318447f;  // 1/sqrt(128)

    const float* qp   = qkv + (size_t)b * QKVN + h * HD;
    const float* newk = qp + HIDDEN;
    const float* newv = qp + 2 * HIDDEN;
    const float4 q4 = *reinterpret_cast<const float4*>(qp + l32 * 4);

    float m = -1e30f, l = 0.f;
    float4 acc[8];
#pragma unroll
    for (int u = 0; u < 8; ++u) acc[u] = make_float4(0.f, 0.f, 0.f, 0.f);

    for (int s0 = wid * 16; s0 < SP; s0 += 64) {
        float4 k4[8], v4[8];
#pragma unroll
        for (int u = 0; u < 8; ++u) {
            const int p = s0 + u * 2 + half;
            const int idx = bt[p >> 4] * PBS + (p & (PBS - 1));
            const bool fresh = (idx == slot_b);
            k4[u] = fresh ? *reinterpret_cast<const float4*>(newk + l32 * 4)
                          : *reinterpret_cast<const float4*>(
                                k_cache + (size_t)idx * HIDDEN + h * HD + l32 * 4);
            v4[u] = fresh ? *reinterpret_cast<const float4*>(newv + l32 * 4)
                          : *reinterpret_cast<const float4*>(
                                v_cache + (size_t)idx * HIDDEN + h * HD + l32 * 4);
        }
        float sc[8];
#pragma unroll
        for (int u = 0; u < 8; ++u) {
            float d = k4[u].x * q4.x + k4[u].y * q4.y + k4[u].z * q4.z + k4[u].w * q4.w;
#pragma unroll
            for (int off = 16; off > 0; off >>= 1) d += __shfl_xor(d, off, 64);
            const int p = s0 + u * 2 + half;
            sc[u] = (base + p < len) ? d * scale : -1e30f;
        }
        float pm = sc[0];
#pragma unroll
        for (int u = 1; u < 8; ++u) pm = fmaxf(pm, sc[u]);
        const float mn = fmaxf(m, pm);
        const float r = __expf(m - mn);
        m = mn;
        l *= r;
        float pu[8];
#pragma unroll
        for (int u = 0; u < 8; ++u) {
            pu[u] = __expf(sc[u] - mn);
            l += pu[u];
        }
#pragma unroll
        for (int u = 0; u < 8; ++u) {
            acc[u].x = fmaf(pu[u], v4[u].x, acc[u].x * r);
            acc[u].y = fmaf(pu[u], v4[u].y, acc[u].y * r);
            acc[u].z = fmaf(pu[u], v4[u].z, acc[u].z * r);
            acc[u].w = fmaf(pu[u], v4[u].w, acc[u].w * r);
        }
    }
    float4 a = acc[0];
#pragma unroll
    for (int u = 1; u < 8; ++u) {
        a.x += acc[u].x; a.y += acc[u].y; a.z += acc[u].z; a.w += acc[u].w;
    }
    {
        const float m2 = __shfl_xor(m, 32, 64);
        const float l2 = __shfl_xor(l, 32, 64);
        float4 a2;
        a2.x = __shfl_xor(a.x, 32, 64);
        a2.y = __shfl_xor(a.y, 32, 64);
        a2.z = __shfl_xor(a.z, 32, 64);
        a2.w = __shfl_xor(a.w, 32, 64);
        const float M  = fmaxf(m, m2);
        const float e1 = __expf(m - M);
        const float e2 = __expf(m2 - M);
        l = l * e1 + l2 * e2;
        a.x = a.x * e1 + a2.x * e2;
        a.y = a.y * e1 + a2.y * e2;
        a.z = a.z * e1 + a2.z * e2;
        a.w = a.w * e1 + a2.w * e2;
        m = M;
    }
    if (half == 0) {
        *reinterpret_cast<float4*>(&stage[wid][l32 * 4]) = a;
        if (l32 == 0) { stage[wid][HD] = m; stage[wid][HD + 1] = l; }
    }
    __syncthreads();
    if (wid == 0) {
        float M4 = stage[0][HD];
#pragma unroll
        for (int w = 1; w < 4; ++w) M4 = fmaxf(M4, stage[w][HD]);
        float L = 0.f, t0 = 0.f, t1 = 0.f;
#pragma unroll
        for (int w = 0; w < 4; ++w) {
            const float e = __expf(stage[w][HD] - M4);
            L  += stage[w][HD + 1] * e;
            t0 += stage[w][lane * 2] * e;
            t1 += stage[w][lane * 2 + 1] * e;
        }
        float* po = part_o + ((size_t)bh * NSPLIT + split) * HD;
        po[lane * 2]     = t0;
        po[lane * 2 + 1] = t1;
        if (lane == 0) {
            part_ml[((size_t)bh * NSPLIT + split) * 2]     = M4;
            part_ml[((size_t)bh * NSPLIT + split) * 2 + 1] = L;
        }
    }
}

// Combine NSPLIT partials per (b,h). One block per bh, HD threads.
__global__ __launch_bounds__(HD) void attn_reduce(const float* __restrict__ part_o,
                                                  const float* __restrict__ part_ml,
                                                  float* __restrict__ attn_out) {
    const int bh = blockIdx.x;
    const int d  = threadIdx.x;
    float M = -1e30f;
#pragma unroll
    for (int i = 0; i < NSPLIT; ++i)
        M = fmaxf(M, part_ml[((size_t)bh * NSPLIT + i) * 2]);
    float L = 0.f, o = 0.f;
#pragma unroll
    for (int i = 0; i < NSPLIT; ++i) {
        const float mi = part_ml[((size_t)bh * NSPLIT + i) * 2];
        const float li = part_ml[((size_t)bh * NSPLIT + i) * 2 + 1];
        const float w  = __expf(mi - M);
        L += li * w;
        o += part_o[((size_t)bh * NSPLIT + i) * HD + d] * w;
    }
    attn_out[(size_t)bh * HD + d] = o / L;
}

extern "C" void kernel_launch(void* const* d_in, const int* in_sizes, int n_in,
                              void* d_out, int out_size, void* d_ws, size_t ws_size,
                              hipStream_t stream) {
    const float* hidden  = (const float*)d_in[0];
    const float* cosb    = (const float*)d_in[1];
    const float* sinb    = (const float*)d_in[2];
    const float* w_qkv   = (const float*)d_in[3];
    const float* b_qkv   = (const float*)d_in[4];
    const float* w_o     = (const float*)d_in[5];
    const float* k_cache = (const float*)d_in[6];
    const float* v_cache = (const float*)d_in[7];
    const int*   btab    = (const int*)d_in[8];
    const int*   slots   = (const int*)d_in[9];
    const int*   lens    = (const int*)d_in[10];

    const int B = in_sizes[0] / HIDDEN;      // 8
    const int max_blocks = in_sizes[8] / B;  // 128
    const int S = max_blocks * PBS;          // 2048

    float* qkv     = (float*)d_ws;                        // [B][QKVN] (roped q,k)
    float* attn    = qkv + (size_t)B * QKVN;              // [B][HIDDEN]
    float* part_o  = attn + (size_t)B * HIDDEN;           // [B*NH*NSPLIT][HD]
    float* part_ml = part_o + (size_t)B * NH * NSPLIT * HD;
    float* out     = (float*)d_out;

    // 1) qkv = hidden @ w_qkv^T + b_qkv, RoPE fused (NR=2, 1536 blocks, 6/CU)
    gemv_qkv_rope<<<1536, 256, 0, stream>>>(hidden, w_qkv, b_qkv, cosb, sinb, qkv);

    // 2) paged attention partials (one-pass online softmax) + reduce
    attn_part<<<B * NH * NSPLIT, 256, 0, stream>>>(qkv, k_cache, v_cache,
                                                   btab, slots, lens,
                                                   part_o, part_ml, S, max_blocks);
    attn_reduce<<<B * NH, HD, 0, stream>>>(part_o, part_ml, attn);

    // 3) out = attn @ w_o^T   (NR=1, 1024 blocks, 4/CU)
    gemv_lds<1><<<HIDDEN / 4, 256, 0, stream>>>(attn, w_o, out, HIDDEN, HIDDEN);
}